// Round 14
// baseline (444.352 us; speedup 1.0000x reference)
//
#include <hip/hip_runtime.h>
#include <math.h>

#define N_NODES 50000
#define N_EDGES 800000
#define NGRAPH  1024
#define D       256
#define OUTD    128
#define NFEAT   9
#define VOCABSZ 100
#define NLAYERS 4
#define NEG_SLOPE 0.2f
#define MAXD    64                          // ELL row capacity (P(deg>63) ~ 1e-22)
#define WT_NBLK (NLAYERS * D * D / 256)     // 1024
#define ATOM_NBLK ((N_NODES + 3) / 4)       // 12500
#define SEEDGROW_NBLK ((N_NODES + 255) / 256) // 196
#define GBM 128
#define GBK 64
#define NGB ((N_NODES + GBM - 1) / GBM)     // 391 gemm blocks
#define SCAT512 ((N_EDGES + 511) / 512)     // 1563 scatter blocks (512 thr)

typedef __attribute__((ext_vector_type(8))) short short8;   // 8 bf16 (4 VGPRs)
typedef __attribute__((ext_vector_type(4))) float f32x4;
typedef __attribute__((ext_vector_type(2))) float f32x2;

static __device__ __forceinline__ unsigned short f2bf(float f) {
    unsigned int u = __float_as_uint(f);
    u = (u + 0x7FFFu + ((u >> 16) & 1u)) >> 16;
    return (unsigned short)u;
}
static __device__ __forceinline__ float bf2f(unsigned short u) {
    return __uint_as_float(((unsigned int)u) << 16);
}

#define GLOAD_LDS16(g, l) __builtin_amdgcn_global_load_lds( \
    (const __attribute__((address_space(1))) void*)(g), \
    (__attribute__((address_space(3))) void*)(l), 16, 0, 0)

// ---------------- fused init: atom encoder || Wt transpose+cvt || seed+growptr ----------------
__global__ __launch_bounds__(256) void init_fused(int* __restrict__ cnt,
                                                  int* __restrict__ ell,
                                                  const float* __restrict__ W,
                                                  unsigned short* __restrict__ Wt,
                                                  const int* __restrict__ x,
                                                  const float* __restrict__ emb,
                                                  unsigned short* __restrict__ h,
                                                  const int* __restrict__ batch,
                                                  int* __restrict__ growptr) {
    int b = blockIdx.x;
    if (b < ATOM_NBLK) {
        int node = b * 4 + (threadIdx.x >> 6);
        int lane = threadIdx.x & 63;
        if (node >= N_NODES) return;
        float4 acc = make_float4(0.f, 0.f, 0.f, 0.f);
        #pragma unroll
        for (int f = 0; f < NFEAT; ++f) {
            int xi = x[node * NFEAT + f];
            float4 v = *(const float4*)&emb[(size_t)(f * VOCABSZ + xi) * D + lane * 4];
            acc.x += v.x; acc.y += v.y; acc.z += v.z; acc.w += v.w;
        }
        ushort4 o;
        o.x = f2bf(acc.x); o.y = f2bf(acc.y); o.z = f2bf(acc.z); o.w = f2bf(acc.w);
        *(ushort4*)&h[node * D + lane * 4] = o;
    } else if (b < ATOM_NBLK + WT_NBLK) {
        int t = (b - ATOM_NBLK) * 256 + threadIdx.x;   // l*65536 + k*256 + n
        int l = t >> 16;
        int k = (t >> 8) & 255;
        int n = t & 255;
        Wt[(l << 16) + n * 256 + k] = f2bf(W[t]);
    } else {
        int n = (b - ATOM_NBLK - WT_NBLK) * 256 + threadIdx.x;
        if (n >= N_NODES) return;
        cnt[n] = 1;                 // self-loop pre-seeded
        ell[n << 6] = n;
        int bb = batch[n];
        int prev = (n == 0) ? -1 : batch[n - 1];
        for (int g = prev + 1; g <= bb; ++g) growptr[g] = n;
        if (n == N_NODES - 1) {
            for (int g = bb + 1; g <= NGRAPH; ++g) growptr[g] = N_NODES;
        }
    }
}

// ---------------- gemm body (device fn; used standalone and fused with scatter) ----------------
static __device__ __forceinline__ void gemm_body(int bid,
                                                 const unsigned short* __restrict__ A,
                                                 const unsigned short* __restrict__ Wt,
                                                 const float* __restrict__ asrc,
                                                 const float* __restrict__ adst,
                                                 unsigned short* __restrict__ C,
                                                 float* __restrict__ s_out,
                                                 float* __restrict__ t_out) {
    __shared__ unsigned short smem[33792];
    __shared__ float s_sh[GBM], t_sh[GBM];
    int row0 = bid * GBM;
    int tid = threadIdx.x;
    int wid = tid >> 6;                  // 0..7
    int lane = tid & 63;
    int wm = wid >> 2, wn = wid & 3;     // 2x4 wave grid, each wave 64x64
    int l15 = lane & 15;
    int lhi = lane >> 4;                 // 0..3

    if (tid < GBM) s_sh[tid] = 0.f;
    else if (tid < 2 * GBM) t_sh[tid - GBM] = 0.f;

    int srcA[2], srcB[4];
    #pragma unroll
    for (int q = 0; q < 2; ++q) {
        int slot = q * 512 + tid;        // 0..1023 -> A rows 0..127
        int r = slot >> 3, c = slot & 7;
        int ra = row0 + r; if (ra > N_NODES - 1) ra = N_NODES - 1;
        srcA[q] = ra * D + ((c ^ (r & 7)) << 3);
    }
    #pragma unroll
    for (int q = 0; q < 4; ++q) {
        int slot = q * 512 + tid;        // 0..2047 -> Wt rows 0..255
        int r = slot >> 3, c = slot & 7;
        srcB[q] = r * D + ((c ^ (r & 7)) << 3);
    }

    f32x4 acc[4][4];
    #pragma unroll
    for (int i = 0; i < 4; ++i)
        #pragma unroll
        for (int j = 0; j < 4; ++j) acc[i][j] = (f32x4){0.f, 0.f, 0.f, 0.f};

    #pragma unroll
    for (int step = 0; step < 4; ++step) {
        int k0 = step * GBK;
        #pragma unroll
        for (int q = 0; q < 2; ++q)
            GLOAD_LDS16(A + srcA[q] + k0, &smem[(q * 512 + wid * 64) * 8]);
        #pragma unroll
        for (int q = 0; q < 4; ++q)
            GLOAD_LDS16(Wt + srcB[q] + k0, &smem[8192 + (q * 512 + wid * 64) * 8]);
        __syncthreads();
        #pragma unroll
        for (int ks = 0; ks < 2; ++ks) {
            short8 af[4], bf[4];
            #pragma unroll
            for (int m = 0; m < 4; ++m) {
                int r = wm * 64 + m * 16 + l15;
                int c = ks * 4 + lhi;
                af[m] = *(const short8*)&smem[r * GBK + ((c ^ (r & 7)) << 3)];
            }
            #pragma unroll
            for (int n = 0; n < 4; ++n) {
                int r = wn * 64 + n * 16 + l15;
                int c = ks * 4 + lhi;
                bf[n] = *(const short8*)&smem[8192 + r * GBK + ((c ^ (r & 7)) << 3)];
            }
            #pragma unroll
            for (int m = 0; m < 4; ++m)
                #pragma unroll
                for (int n = 0; n < 4; ++n)
                    acc[m][n] = __builtin_amdgcn_mfma_f32_16x16x32_bf16(af[m], bf[n], acc[m][n], 0, 0, 0);
        }
        __syncthreads();
    }

    // epilogue 1: stage C tile in LDS (row-major, stride 264 shorts), coalesced short8 store
    unsigned short* c_s = smem;   // 128*264 = 33792 shorts
    #pragma unroll
    for (int m = 0; m < 4; ++m) {
        #pragma unroll
        for (int r = 0; r < 4; ++r) {
            int lr = wm * 64 + m * 16 + lhi * 4 + r;
            #pragma unroll
            for (int n = 0; n < 4; ++n) {
                int lc = wn * 64 + n * 16 + l15;
                c_s[lr * 264 + lc] = f2bf(acc[m][n][r]);
            }
        }
    }
    __syncthreads();
    #pragma unroll
    for (int p = 0; p < 8; ++p) {
        int slot = p * 512 + tid;          // 0..4095
        int r2 = slot >> 5;                // 0..127
        int c2 = slot & 31;                // 0..31
        int grow = row0 + r2;
        if (grow < N_NODES) {
            short8 vv = *(const short8*)&c_s[r2 * 264 + c2 * 8];
            *(short8*)&C[(size_t)grow * D + c2 * 8] = vv;
        }
    }

    // epilogue 2: s,t full-row dots via LDS reduction, direct store
    float av[4], bv[4];
    #pragma unroll
    for (int n = 0; n < 4; ++n) {
        int gcol = wn * 64 + n * 16 + l15;
        av[n] = asrc[gcol];
        bv[n] = adst[gcol];
    }
    #pragma unroll
    for (int m = 0; m < 4; ++m) {
        #pragma unroll
        for (int r = 0; r < 4; ++r) {
            float ps = 0.f, pt = 0.f;
            #pragma unroll
            for (int n = 0; n < 4; ++n) {
                ps += acc[m][n][r] * av[n];
                pt += acc[m][n][r] * bv[n];
            }
            #pragma unroll
            for (int off = 1; off < 16; off <<= 1) {
                ps += __shfl_xor(ps, off, 64);
                pt += __shfl_xor(pt, off, 64);
            }
            if (l15 == 0) {
                int lr = wm * 64 + m * 16 + lhi * 4 + r;
                atomicAdd(&s_sh[lr], ps);
                atomicAdd(&t_sh[lr], pt);
            }
        }
    }
    __syncthreads();
    if (tid < GBM) {
        int gr = row0 + tid;
        if (gr < N_NODES) s_out[gr] = s_sh[tid];
    } else if (tid < 2 * GBM) {
        int gr = row0 + tid - GBM;
        if (gr < N_NODES) t_out[gr] = t_sh[tid - GBM];
    }
}

__global__ __launch_bounds__(512) void gemm_bf16(const unsigned short* __restrict__ A,
                                                 const unsigned short* __restrict__ Wt,
                                                 const float* __restrict__ asrc,
                                                 const float* __restrict__ adst,
                                                 unsigned short* __restrict__ C,
                                                 float* __restrict__ s_out,
                                                 float* __restrict__ t_out) {
    gemm_body(blockIdx.x, A, Wt, asrc, adst, C, s_out, t_out);
}

// layer-0 gemm with ELL scatter fused in trailing blocks (scatter output first
// consumed by aggregate_kernel of layer 0, which launches after this kernel).
__global__ __launch_bounds__(512) void gemm0_scatter(const unsigned short* __restrict__ A,
                                                     const unsigned short* __restrict__ Wt,
                                                     const float* __restrict__ asrc,
                                                     const float* __restrict__ adst,
                                                     unsigned short* __restrict__ C,
                                                     float* __restrict__ s_out,
                                                     float* __restrict__ t_out,
                                                     const int* __restrict__ src,
                                                     const int* __restrict__ dst,
                                                     int* __restrict__ cnt,
                                                     int* __restrict__ ell) {
    int b = blockIdx.x;
    if (b < NGB) {
        gemm_body(b, A, Wt, asrc, adst, C, s_out, t_out);
    } else {
        int e = (b - NGB) * 512 + threadIdx.x;
        if (e < N_EDGES) {
            int d = dst[e];
            int pos = atomicAdd(&cnt[d], 1);
            if (pos < MAXD) ell[(d << 6) + pos] = src[e];
        }
    }
}

// ---------------- flash-style attention + aggregate (wave per dst, ELL rows) ----------------
__global__ __launch_bounds__(256) void aggregate_kernel(const unsigned short* __restrict__ hW,
                                                        const float* __restrict__ s,
                                                        const float* __restrict__ t,
                                                        const int* __restrict__ cnt,
                                                        const int* __restrict__ ell,
                                                        const float* __restrict__ bias,
                                                        unsigned short* __restrict__ hout) {
    int v = (blockIdx.x * blockDim.x + threadIdx.x) >> 6;
    int lane = threadIdx.x & 63;
    if (v >= N_NODES) return;
    int beg = v << 6;
    int deg = cnt[v]; if (deg > MAXD) deg = MAXD;
    float tv = t[v];
    float m = -1e30f;
    float denom = 0.f;
    f32x2 acc2[4];
    #pragma unroll
    for (int j = 0; j < 4; ++j) acc2[j] = (f32x2){0.f, 0.f};
    int half = lane >> 5;
    int l32 = lane & 31;
    const unsigned short* hbase = hW + (size_t)l32 * 8;

    for (int base = 0; base < deg; base += 64) {
        int rem = deg - base; if (rem > 64) rem = 64;
        int u = 0; float e = -1e30f;
        if (lane < rem) {
            u = ell[beg + base + lane];
            float ev = s[u] + tv;
            e = (ev > 0.f) ? ev : NEG_SLOPE * ev;
        }
        float cm = e;
        #pragma unroll
        for (int off = 32; off; off >>= 1) cm = fmaxf(cm, __shfl_xor(cm, off, 64));
        float newm = fmaxf(m, cm);
        float scale = __expf(m - newm);
        float p = (lane < rem) ? __expf(e - newm) : 0.f;
        float ws = p;
        #pragma unroll
        for (int off = 32; off; off >>= 1) ws += __shfl_xor(ws, off, 64);
        denom = denom * scale + ws;
        m = newm;
        f32x2 sc2 = (f32x2){scale, scale};
        #pragma unroll
        for (int j = 0; j < 4; ++j) acc2[j] *= sc2;
        for (int i = 0; i < rem; i += 4) {
            int idx0 = i + half;
            int idx1 = i + 2 + half;
            float p0 = __shfl(p, idx0, 64);
            int   u0 = __shfl(u, idx0, 64);
            float p1 = __shfl(p, idx1, 64);
            int   u1 = __shfl(u, idx1, 64);
            uint4 w0 = *(const uint4*)(hbase + ((size_t)u0 << 8));
            uint4 w1 = *(const uint4*)(hbase + ((size_t)u1 << 8));
            f32x2 p20 = (f32x2){p0, p0};
            f32x2 p21 = (f32x2){p1, p1};
            unsigned int ww; f32x2 h2;
            ww = w0.x; h2 = (f32x2){__uint_as_float(ww << 16), __uint_as_float(ww & 0xffff0000u)};
            acc2[0] += p20 * h2;
            ww = w0.y; h2 = (f32x2){__uint_as_float(ww << 16), __uint_as_float(ww & 0xffff0000u)};
            acc2[1] += p20 * h2;
            ww = w0.z; h2 = (f32x2){__uint_as_float(ww << 16), __uint_as_float(ww & 0xffff0000u)};
            acc2[2] += p20 * h2;
            ww = w0.w; h2 = (f32x2){__uint_as_float(ww << 16), __uint_as_float(ww & 0xffff0000u)};
            acc2[3] += p20 * h2;
            ww = w1.x; h2 = (f32x2){__uint_as_float(ww << 16), __uint_as_float(ww & 0xffff0000u)};
            acc2[0] += p21 * h2;
            ww = w1.y; h2 = (f32x2){__uint_as_float(ww << 16), __uint_as_float(ww & 0xffff0000u)};
            acc2[1] += p21 * h2;
            ww = w1.z; h2 = (f32x2){__uint_as_float(ww << 16), __uint_as_float(ww & 0xffff0000u)};
            acc2[2] += p21 * h2;
            ww = w1.w; h2 = (f32x2){__uint_as_float(ww << 16), __uint_as_float(ww & 0xffff0000u)};
            acc2[3] += p21 * h2;
        }
    }
    #pragma unroll
    for (int j = 0; j < 4; ++j) {
        acc2[j].x += __shfl_xor(acc2[j].x, 32, 64);
        acc2[j].y += __shfl_xor(acc2[j].y, 32, 64);
    }
    float inv = 1.f / denom;
    if (half == 0) {
        float4 b0 = *(const float4*)&bias[l32 * 8];
        float4 b1 = *(const float4*)&bias[l32 * 8 + 4];
        float bb[8] = {b0.x, b0.y, b0.z, b0.w, b1.x, b1.y, b1.z, b1.w};
        float av[8] = {acc2[0].x, acc2[0].y, acc2[1].x, acc2[1].y,
                       acc2[2].x, acc2[2].y, acc2[3].x, acc2[3].y};
        short8 o;
        #pragma unroll
        for (int j = 0; j < 8; ++j) {
            float val = fmaxf(av[j] * inv + bb[j], 0.f);
            o[j] = (short)f2bf(val);
        }
        *(short8*)&hout[(size_t)v * D + l32 * 8] = o;
    }
}

// ---------------- pooling: 1 graph per block, 4 waves parallel over nodes ----------------
__global__ __launch_bounds__(256) void pool_kernel(const unsigned short* __restrict__ h,
                                                   const int* __restrict__ growptr,
                                                   float* __restrict__ feats) {
    int g = blockIdx.x;
    int wid = threadIdx.x >> 6;    // 0..3
    int lane = threadIdx.x & 63;
    int beg = growptr[g], end = growptr[g + 1];
    float4 add = make_float4(0.f, 0.f, 0.f, 0.f);
    float4 mx = make_float4(-1e30f, -1e30f, -1e30f, -1e30f);
    for (int v = beg + wid; v < end; v += 4) {
        ushort4 hv = *(const ushort4*)&h[(size_t)v * D + lane * 4];
        float a0 = bf2f(hv.x), a1 = bf2f(hv.y), a2 = bf2f(hv.z), a3 = bf2f(hv.w);
        add.x += a0; add.y += a1; add.z += a2; add.w += a3;
        mx.x = fmaxf(mx.x, a0); mx.y = fmaxf(mx.y, a1);
        mx.z = fmaxf(mx.z, a2); mx.w = fmaxf(mx.w, a3);
    }
    __shared__ float sadd[4][D];
    __shared__ float smax[4][D];
    *(float4*)&sadd[wid][lane * 4] = add;
    *(float4*)&smax[wid][lane * 4] = mx;
    __syncthreads();
    if (wid == 0) {
        float4 A0 = *(const float4*)&sadd[0][lane * 4];
        float4 A1 = *(const float4*)&sadd[1][lane * 4];
        float4 A2 = *(const float4*)&sadd[2][lane * 4];
        float4 A3 = *(const float4*)&sadd[3][lane * 4];
        float4 M0 = *(const float4*)&smax[0][lane * 4];
        float4 M1 = *(const float4*)&smax[1][lane * 4];
        float4 M2 = *(const float4*)&smax[2][lane * 4];
        float4 M3 = *(const float4*)&smax[3][lane * 4];
        float4 ta = make_float4(A0.x + A1.x + A2.x + A3.x, A0.y + A1.y + A2.y + A3.y,
                                A0.z + A1.z + A2.z + A3.z, A0.w + A1.w + A2.w + A3.w);
        float4 tm = make_float4(fmaxf(fmaxf(M0.x, M1.x), fmaxf(M2.x, M3.x)),
                                fmaxf(fmaxf(M0.y, M1.y), fmaxf(M2.y, M3.y)),
                                fmaxf(fmaxf(M0.z, M1.z), fmaxf(M2.z, M3.z)),
                                fmaxf(fmaxf(M0.w, M1.w), fmaxf(M2.w, M3.w)));
        float cnt = (float)(end - beg);
        float invc = 1.f / fmaxf(cnt, 1.f);
        if (cnt <= 0.f) tm = make_float4(0.f, 0.f, 0.f, 0.f);
        float4 mean = make_float4(ta.x * invc, ta.y * invc, ta.z * invc, ta.w * invc);
        float* fr = feats + (size_t)g * 3 * D;
        *(float4*)&fr[0 * D + 4 * lane] = mean;
        *(float4*)&fr[1 * D + 4 * lane] = ta;
        *(float4*)&fr[2 * D + 4 * lane] = tm;
    }
}

// ---------------- final linear: 1 graph/block, 512 threads, k split 4-way ----------------
__global__ __launch_bounds__(512) void final_linear(const float* __restrict__ feats,
                                                    const float* __restrict__ lw,
                                                    const float* __restrict__ lb,
                                                    float* __restrict__ out) {
    int g = blockIdx.x;
    int tid = threadIdx.x;
    int kq = tid >> 7;       // 0..3
    int j = tid & 127;
    __shared__ float sf[3 * D];
    __shared__ float sacc[4][OUTD];
    for (int i = tid; i < 3 * D; i += 512) sf[i] = feats[(size_t)g * 3 * D + i];
    __syncthreads();
    float acc = 0.f;
    const float* lwp = lw + (kq * 192) * OUTD + j;
    const float* sfp = sf + kq * 192;
    #pragma unroll 8
    for (int i = 0; i < 192; ++i)
        acc += sfp[i] * lwp[i * OUTD];
    sacc[kq][j] = acc;
    __syncthreads();
    if (kq == 0)
        out[g * OUTD + j] = lb[j] + sacc[0][j] + sacc[1][j] + sacc[2][j] + sacc[3][j];
}

extern "C" void kernel_launch(void* const* d_in, const int* in_sizes, int n_in,
                              void* d_out, int out_size, void* d_ws, size_t ws_size,
                              hipStream_t stream) {
    const int*   x        = (const int*)d_in[0];
    const int*   edge_idx = (const int*)d_in[1];
    const int*   batch    = (const int*)d_in[2];
    const float* atom_emb = (const float*)d_in[3];
    const float* Ws       = (const float*)d_in[4];
    const float* a_src    = (const float*)d_in[5];
    const float* a_dst    = (const float*)d_in[6];
    const float* biases   = (const float*)d_in[7];
    const float* lin_w    = (const float*)d_in[8];
    const float* lin_b    = (const float*)d_in[9];
    float* out = (float*)d_out;

    char* ws = (char*)d_ws;
    size_t off = 0;
    auto alloc = [&](size_t bytes) -> void* {
        void* p = ws + off;
        off += (bytes + 255) & ~(size_t)255;
        return p;
    };
    unsigned short* bufA  = (unsigned short*)alloc(sizeof(short) * (size_t)N_NODES * D);
    unsigned short* bufB  = (unsigned short*)alloc(sizeof(short) * (size_t)N_NODES * D);
    unsigned short* Wt    = (unsigned short*)alloc(sizeof(short) * NLAYERS * D * D);
    float* s      = (float*)alloc(sizeof(float) * N_NODES);
    float* t      = (float*)alloc(sizeof(float) * N_NODES);
    int*   cnt    = (int*)alloc(sizeof(int) * N_NODES);
    int*   ell    = (int*)alloc(sizeof(int) * (size_t)N_NODES * MAXD);
    int*   growp  = (int*)alloc(sizeof(int) * (NGRAPH + 1));
    float* feats  = (float*)alloc(sizeof(float) * (size_t)NGRAPH * 3 * D);

    const int* esrc = edge_idx;
    const int* edst = edge_idx + N_EDGES;

    init_fused<<<ATOM_NBLK + WT_NBLK + SEEDGROW_NBLK, 256, 0, stream>>>(
        cnt, ell, Ws, Wt, x, atom_emb, bufA, batch, growp);

    for (int l = 0; l < NLAYERS; ++l) {
        if (l == 0) {
            gemm0_scatter<<<NGB + SCAT512, 512, 0, stream>>>(
                bufA, Wt, a_src, a_dst, bufB, s, t, esrc, edst, cnt, ell);
        } else {
            gemm_bf16<<<NGB, 512, 0, stream>>>(
                bufA, Wt + (size_t)l * D * D,
                a_src + l * D, a_dst + l * D, bufB, s, t);
        }
        aggregate_kernel<<<(N_NODES + 3) / 4, 256, 0, stream>>>(bufB, s, t,
                                             cnt, ell, biases + l * D, bufA);
    }

    pool_kernel<<<NGRAPH, 256, 0, stream>>>(bufA, growp, feats);
    final_linear<<<NGRAPH, 512, 0, stream>>>(feats, lin_w, lin_b, out);
}

// Round 15
// 438.272 us; speedup vs baseline: 1.0139x; 1.0139x over previous
//
#include <hip/hip_runtime.h>
#include <math.h>

#define N_NODES 50000
#define N_EDGES 800000
#define NGRAPH  1024
#define D       256
#define OUTD    128
#define NFEAT   9
#define VOCABSZ 100
#define NLAYERS 4
#define NEG_SLOPE 0.2f
#define MAXD    64                          // ELL row capacity (P(deg>63) ~ 1e-22)
#define SEED_NBLK ((N_NODES + 255) / 256)   // 196
#define WT_NBLK (NLAYERS * D * D / 256)     // 1024
#define ATOM_NBLK ((N_NODES + 3) / 4)       // 12500
#define SCAT_NBLK ((N_EDGES + 255) / 256)   // 3125
#define GROW_NBLK ((N_NODES + 255) / 256)   // 196

typedef __attribute__((ext_vector_type(8))) short short8;   // 8 bf16 (4 VGPRs)
typedef __attribute__((ext_vector_type(4))) float f32x4;
typedef __attribute__((ext_vector_type(2))) float f32x2;

static __device__ __forceinline__ unsigned short f2bf(float f) {
    unsigned int u = __float_as_uint(f);
    u = (u + 0x7FFFu + ((u >> 16) & 1u)) >> 16;
    return (unsigned short)u;
}
static __device__ __forceinline__ float bf2f(unsigned short u) {
    return __uint_as_float(((unsigned int)u) << 16);
}

#define GLOAD_LDS16(g, l) __builtin_amdgcn_global_load_lds( \
    (const __attribute__((address_space(1))) void*)(g), \
    (__attribute__((address_space(3))) void*)(l), 16, 0, 0)

// ---------------- seed: cnt=1, self-loop in ELL slot 0 ----------------
__global__ void seed_kernel(int* __restrict__ cnt, int* __restrict__ ell) {
    int i = blockIdx.x * blockDim.x + threadIdx.x;
    if (i < N_NODES) {
        cnt[i] = 1;
        ell[i << 6] = i;
    }
}

// ---------------- fused: ELL scatter || atom encoder || Wt transpose+cvt || growptr ----------------
__global__ __launch_bounds__(256) void init_scatter_fused(int* __restrict__ cnt,
                                                          int* __restrict__ ell,
                                                          const float* __restrict__ W,
                                                          unsigned short* __restrict__ Wt,
                                                          const int* __restrict__ x,
                                                          const float* __restrict__ emb,
                                                          unsigned short* __restrict__ h,
                                                          const int* __restrict__ src,
                                                          const int* __restrict__ dst,
                                                          const int* __restrict__ batch,
                                                          int* __restrict__ growptr) {
    int b = blockIdx.x;
    if (b < SCAT_NBLK) {
        // edge scatter first (longest pole gets scheduled earliest)
        int e = b * 256 + threadIdx.x;
        if (e < N_EDGES) {
            int d = dst[e];
            int pos = atomicAdd(&cnt[d], 1);
            if (pos < MAXD) ell[(d << 6) + pos] = src[e];
        }
    } else if (b < SCAT_NBLK + ATOM_NBLK) {
        int node = (b - SCAT_NBLK) * 4 + (threadIdx.x >> 6);
        int lane = threadIdx.x & 63;
        if (node >= N_NODES) return;
        float4 acc = make_float4(0.f, 0.f, 0.f, 0.f);
        #pragma unroll
        for (int f = 0; f < NFEAT; ++f) {
            int xi = x[node * NFEAT + f];
            float4 v = *(const float4*)&emb[(size_t)(f * VOCABSZ + xi) * D + lane * 4];
            acc.x += v.x; acc.y += v.y; acc.z += v.z; acc.w += v.w;
        }
        ushort4 o;
        o.x = f2bf(acc.x); o.y = f2bf(acc.y); o.z = f2bf(acc.z); o.w = f2bf(acc.w);
        *(ushort4*)&h[node * D + lane * 4] = o;
    } else if (b < SCAT_NBLK + ATOM_NBLK + WT_NBLK) {
        int t = (b - SCAT_NBLK - ATOM_NBLK) * 256 + threadIdx.x;   // l*65536 + k*256 + n
        int l = t >> 16;
        int k = (t >> 8) & 255;
        int n = t & 255;
        Wt[(l << 16) + n * 256 + k] = f2bf(W[t]);
    } else {
        int n = (b - SCAT_NBLK - ATOM_NBLK - WT_NBLK) * 256 + threadIdx.x;
        if (n >= N_NODES) return;
        int bb = batch[n];
        int prev = (n == 0) ? -1 : batch[n - 1];
        for (int g = prev + 1; g <= bb; ++g) growptr[g] = n;
        if (n == N_NODES - 1) {
            for (int g = bb + 1; g <= NGRAPH; ++g) growptr[g] = N_NODES;
        }
    }
}

// ---------------- bf16 MFMA GEMM, full-width 128x256 tile, 8 waves ----------------
#define GBM 128
#define GBK 64
__global__ __launch_bounds__(512) void gemm_bf16(const unsigned short* __restrict__ A,
                                                 const unsigned short* __restrict__ Wt,
                                                 const float* __restrict__ asrc,
                                                 const float* __restrict__ adst,
                                                 unsigned short* __restrict__ C,
                                                 float* __restrict__ s_out,
                                                 float* __restrict__ t_out) {
    __shared__ unsigned short smem[33792];
    __shared__ float s_sh[GBM], t_sh[GBM];
    int row0 = blockIdx.x * GBM;
    int tid = threadIdx.x;
    int wid = tid >> 6;                  // 0..7
    int lane = tid & 63;
    int wm = wid >> 2, wn = wid & 3;     // 2x4 wave grid, each wave 64x64
    int l15 = lane & 15;
    int lhi = lane >> 4;                 // 0..3

    if (tid < GBM) s_sh[tid] = 0.f;
    else if (tid < 2 * GBM) t_sh[tid - GBM] = 0.f;

    int srcA[2], srcB[4];
    #pragma unroll
    for (int q = 0; q < 2; ++q) {
        int slot = q * 512 + tid;        // 0..1023 -> A rows 0..127
        int r = slot >> 3, c = slot & 7;
        int ra = row0 + r; if (ra > N_NODES - 1) ra = N_NODES - 1;
        srcA[q] = ra * D + ((c ^ (r & 7)) << 3);
    }
    #pragma unroll
    for (int q = 0; q < 4; ++q) {
        int slot = q * 512 + tid;        // 0..2047 -> Wt rows 0..255
        int r = slot >> 3, c = slot & 7;
        srcB[q] = r * D + ((c ^ (r & 7)) << 3);
    }

    f32x4 acc[4][4];
    #pragma unroll
    for (int i = 0; i < 4; ++i)
        #pragma unroll
        for (int j = 0; j < 4; ++j) acc[i][j] = (f32x4){0.f, 0.f, 0.f, 0.f};

    #pragma unroll
    for (int step = 0; step < 4; ++step) {
        int k0 = step * GBK;
        #pragma unroll
        for (int q = 0; q < 2; ++q)
            GLOAD_LDS16(A + srcA[q] + k0, &smem[(q * 512 + wid * 64) * 8]);
        #pragma unroll
        for (int q = 0; q < 4; ++q)
            GLOAD_LDS16(Wt + srcB[q] + k0, &smem[8192 + (q * 512 + wid * 64) * 8]);
        __syncthreads();
        #pragma unroll
        for (int ks = 0; ks < 2; ++ks) {
            short8 af[4], bf[4];
            #pragma unroll
            for (int m = 0; m < 4; ++m) {
                int r = wm * 64 + m * 16 + l15;
                int c = ks * 4 + lhi;
                af[m] = *(const short8*)&smem[r * GBK + ((c ^ (r & 7)) << 3)];
            }
            #pragma unroll
            for (int n = 0; n < 4; ++n) {
                int r = wn * 64 + n * 16 + l15;
                int c = ks * 4 + lhi;
                bf[n] = *(const short8*)&smem[8192 + r * GBK + ((c ^ (r & 7)) << 3)];
            }
            #pragma unroll
            for (int m = 0; m < 4; ++m)
                #pragma unroll
                for (int n = 0; n < 4; ++n)
                    acc[m][n] = __builtin_amdgcn_mfma_f32_16x16x32_bf16(af[m], bf[n], acc[m][n], 0, 0, 0);
        }
        __syncthreads();
    }

    // epilogue 1: stage C tile in LDS (row-major, stride 264 shorts), coalesced short8 store
    unsigned short* c_s = smem;   // 128*264 = 33792 shorts
    #pragma unroll
    for (int m = 0; m < 4; ++m) {
        #pragma unroll
        for (int r = 0; r < 4; ++r) {
            int lr = wm * 64 + m * 16 + lhi * 4 + r;
            #pragma unroll
            for (int n = 0; n < 4; ++n) {
                int lc = wn * 64 + n * 16 + l15;
                c_s[lr * 264 + lc] = f2bf(acc[m][n][r]);
            }
        }
    }
    __syncthreads();
    #pragma unroll
    for (int p = 0; p < 8; ++p) {
        int slot = p * 512 + tid;          // 0..4095
        int r2 = slot >> 5;                // 0..127
        int c2 = slot & 31;                // 0..31
        int grow = row0 + r2;
        if (grow < N_NODES) {
            short8 vv = *(const short8*)&c_s[r2 * 264 + c2 * 8];
            *(short8*)&C[(size_t)grow * D + c2 * 8] = vv;
        }
    }

    // epilogue 2: s,t full-row dots via LDS reduction, direct store
    float av[4], bv[4];
    #pragma unroll
    for (int n = 0; n < 4; ++n) {
        int gcol = wn * 64 + n * 16 + l15;
        av[n] = asrc[gcol];
        bv[n] = adst[gcol];
    }
    #pragma unroll
    for (int m = 0; m < 4; ++m) {
        #pragma unroll
        for (int r = 0; r < 4; ++r) {
            float ps = 0.f, pt = 0.f;
            #pragma unroll
            for (int n = 0; n < 4; ++n) {
                ps += acc[m][n][r] * av[n];
                pt += acc[m][n][r] * bv[n];
            }
            #pragma unroll
            for (int off = 1; off < 16; off <<= 1) {
                ps += __shfl_xor(ps, off, 64);
                pt += __shfl_xor(pt, off, 64);
            }
            if (l15 == 0) {
                int lr = wm * 64 + m * 16 + lhi * 4 + r;
                atomicAdd(&s_sh[lr], ps);
                atomicAdd(&t_sh[lr], pt);
            }
        }
    }
    __syncthreads();
    if (tid < GBM) {
        int gr = row0 + tid;
        if (gr < N_NODES) s_out[gr] = s_sh[tid];
    } else if (tid < 2 * GBM) {
        int gr = row0 + tid - GBM;
        if (gr < N_NODES) t_out[gr] = t_sh[tid - GBM];
    }
}

// ---------------- flash-style attention + aggregate (wave per dst, ELL rows) ----------------
__global__ __launch_bounds__(256) void aggregate_kernel(const unsigned short* __restrict__ hW,
                                                        const float* __restrict__ s,
                                                        const float* __restrict__ t,
                                                        const int* __restrict__ cnt,
                                                        const int* __restrict__ ell,
                                                        const float* __restrict__ bias,
                                                        unsigned short* __restrict__ hout) {
    int v = (blockIdx.x * blockDim.x + threadIdx.x) >> 6;
    int lane = threadIdx.x & 63;
    if (v >= N_NODES) return;
    int beg = v << 6;
    int deg = cnt[v]; if (deg > MAXD) deg = MAXD;
    float tv = t[v];
    float m = -1e30f;
    float denom = 0.f;
    f32x2 acc2[4];
    #pragma unroll
    for (int j = 0; j < 4; ++j) acc2[j] = (f32x2){0.f, 0.f};
    int half = lane >> 5;
    int l32 = lane & 31;
    const unsigned short* hbase = hW + (size_t)l32 * 8;

    for (int base = 0; base < deg; base += 64) {
        int rem = deg - base; if (rem > 64) rem = 64;
        int u = 0; float e = -1e30f;
        if (lane < rem) {
            u = ell[beg + base + lane];
            float ev = s[u] + tv;
            e = (ev > 0.f) ? ev : NEG_SLOPE * ev;
        }
        float cm = e;
        #pragma unroll
        for (int off = 32; off; off >>= 1) cm = fmaxf(cm, __shfl_xor(cm, off, 64));
        float newm = fmaxf(m, cm);
        float scale = __expf(m - newm);
        float p = (lane < rem) ? __expf(e - newm) : 0.f;
        float ws = p;
        #pragma unroll
        for (int off = 32; off; off >>= 1) ws += __shfl_xor(ws, off, 64);
        denom = denom * scale + ws;
        m = newm;
        f32x2 sc2 = (f32x2){scale, scale};
        #pragma unroll
        for (int j = 0; j < 4; ++j) acc2[j] *= sc2;
        for (int i = 0; i < rem; i += 4) {
            int idx0 = i + half;
            int idx1 = i + 2 + half;
            float p0 = __shfl(p, idx0, 64);
            int   u0 = __shfl(u, idx0, 64);
            float p1 = __shfl(p, idx1, 64);
            int   u1 = __shfl(u, idx1, 64);
            uint4 w0 = *(const uint4*)(hbase + ((size_t)u0 << 8));
            uint4 w1 = *(const uint4*)(hbase + ((size_t)u1 << 8));
            f32x2 p20 = (f32x2){p0, p0};
            f32x2 p21 = (f32x2){p1, p1};
            unsigned int ww; f32x2 h2;
            ww = w0.x; h2 = (f32x2){__uint_as_float(ww << 16), __uint_as_float(ww & 0xffff0000u)};
            acc2[0] += p20 * h2;
            ww = w0.y; h2 = (f32x2){__uint_as_float(ww << 16), __uint_as_float(ww & 0xffff0000u)};
            acc2[1] += p20 * h2;
            ww = w0.z; h2 = (f32x2){__uint_as_float(ww << 16), __uint_as_float(ww & 0xffff0000u)};
            acc2[2] += p20 * h2;
            ww = w0.w; h2 = (f32x2){__uint_as_float(ww << 16), __uint_as_float(ww & 0xffff0000u)};
            acc2[3] += p20 * h2;
            ww = w1.x; h2 = (f32x2){__uint_as_float(ww << 16), __uint_as_float(ww & 0xffff0000u)};
            acc2[0] += p21 * h2;
            ww = w1.y; h2 = (f32x2){__uint_as_float(ww << 16), __uint_as_float(ww & 0xffff0000u)};
            acc2[1] += p21 * h2;
            ww = w1.z; h2 = (f32x2){__uint_as_float(ww << 16), __uint_as_float(ww & 0xffff0000u)};
            acc2[2] += p21 * h2;
            ww = w1.w; h2 = (f32x2){__uint_as_float(ww << 16), __uint_as_float(ww & 0xffff0000u)};
            acc2[3] += p21 * h2;
        }
    }
    #pragma unroll
    for (int j = 0; j < 4; ++j) {
        acc2[j].x += __shfl_xor(acc2[j].x, 32, 64);
        acc2[j].y += __shfl_xor(acc2[j].y, 32, 64);
    }
    float inv = 1.f / denom;
    if (half == 0) {
        float4 b0 = *(const float4*)&bias[l32 * 8];
        float4 b1 = *(const float4*)&bias[l32 * 8 + 4];
        float bb[8] = {b0.x, b0.y, b0.z, b0.w, b1.x, b1.y, b1.z, b1.w};
        float av[8] = {acc2[0].x, acc2[0].y, acc2[1].x, acc2[1].y,
                       acc2[2].x, acc2[2].y, acc2[3].x, acc2[3].y};
        short8 o;
        #pragma unroll
        for (int j = 0; j < 8; ++j) {
            float val = fmaxf(av[j] * inv + bb[j], 0.f);
            o[j] = (short)f2bf(val);
        }
        *(short8*)&hout[(size_t)v * D + l32 * 8] = o;
    }
}

// ---------------- pooling: 1 graph per block, 4 waves parallel over nodes ----------------
__global__ __launch_bounds__(256) void pool_kernel(const unsigned short* __restrict__ h,
                                                   const int* __restrict__ growptr,
                                                   float* __restrict__ feats) {
    int g = blockIdx.x;
    int wid = threadIdx.x >> 6;    // 0..3
    int lane = threadIdx.x & 63;
    int beg = growptr[g], end = growptr[g + 1];
    float4 add = make_float4(0.f, 0.f, 0.f, 0.f);
    float4 mx = make_float4(-1e30f, -1e30f, -1e30f, -1e30f);
    for (int v = beg + wid; v < end; v += 4) {
        ushort4 hv = *(const ushort4*)&h[(size_t)v * D + lane * 4];
        float a0 = bf2f(hv.x), a1 = bf2f(hv.y), a2 = bf2f(hv.z), a3 = bf2f(hv.w);
        add.x += a0; add.y += a1; add.z += a2; add.w += a3;
        mx.x = fmaxf(mx.x, a0); mx.y = fmaxf(mx.y, a1);
        mx.z = fmaxf(mx.z, a2); mx.w = fmaxf(mx.w, a3);
    }
    __shared__ float sadd[4][D];
    __shared__ float smax[4][D];
    *(float4*)&sadd[wid][lane * 4] = add;
    *(float4*)&smax[wid][lane * 4] = mx;
    __syncthreads();
    if (wid == 0) {
        float4 A0 = *(const float4*)&sadd[0][lane * 4];
        float4 A1 = *(const float4*)&sadd[1][lane * 4];
        float4 A2 = *(const float4*)&sadd[2][lane * 4];
        float4 A3 = *(const float4*)&sadd[3][lane * 4];
        float4 M0 = *(const float4*)&smax[0][lane * 4];
        float4 M1 = *(const float4*)&smax[1][lane * 4];
        float4 M2 = *(const float4*)&smax[2][lane * 4];
        float4 M3 = *(const float4*)&smax[3][lane * 4];
        float4 ta = make_float4(A0.x + A1.x + A2.x + A3.x, A0.y + A1.y + A2.y + A3.y,
                                A0.z + A1.z + A2.z + A3.z, A0.w + A1.w + A2.w + A3.w);
        float4 tm = make_float4(fmaxf(fmaxf(M0.x, M1.x), fmaxf(M2.x, M3.x)),
                                fmaxf(fmaxf(M0.y, M1.y), fmaxf(M2.y, M3.y)),
                                fmaxf(fmaxf(M0.z, M1.z), fmaxf(M2.z, M3.z)),
                                fmaxf(fmaxf(M0.w, M1.w), fmaxf(M2.w, M3.w)));
        float cnt = (float)(end - beg);
        float invc = 1.f / fmaxf(cnt, 1.f);
        if (cnt <= 0.f) tm = make_float4(0.f, 0.f, 0.f, 0.f);
        float4 mean = make_float4(ta.x * invc, ta.y * invc, ta.z * invc, ta.w * invc);
        float* fr = feats + (size_t)g * 3 * D;
        *(float4*)&fr[0 * D + 4 * lane] = mean;
        *(float4*)&fr[1 * D + 4 * lane] = ta;
        *(float4*)&fr[2 * D + 4 * lane] = tm;
    }
}

// ---------------- final linear: 1 graph/block, 512 threads, k split 4-way ----------------
__global__ __launch_bounds__(512) void final_linear(const float* __restrict__ feats,
                                                    const float* __restrict__ lw,
                                                    const float* __restrict__ lb,
                                                    float* __restrict__ out) {
    int g = blockIdx.x;
    int tid = threadIdx.x;
    int kq = tid >> 7;       // 0..3
    int j = tid & 127;
    __shared__ float sf[3 * D];
    __shared__ float sacc[4][OUTD];
    for (int i = tid; i < 3 * D; i += 512) sf[i] = feats[(size_t)g * 3 * D + i];
    __syncthreads();
    float acc = 0.f;
    const float* lwp = lw + (kq * 192) * OUTD + j;
    const float* sfp = sf + kq * 192;
    #pragma unroll 8
    for (int i = 0; i < 192; ++i)
        acc += sfp[i] * lwp[i * OUTD];
    sacc[kq][j] = acc;
    __syncthreads();
    if (kq == 0)
        out[g * OUTD + j] = lb[j] + sacc[0][j] + sacc[1][j] + sacc[2][j] + sacc[3][j];
}

extern "C" void kernel_launch(void* const* d_in, const int* in_sizes, int n_in,
                              void* d_out, int out_size, void* d_ws, size_t ws_size,
                              hipStream_t stream) {
    const int*   x        = (const int*)d_in[0];
    const int*   edge_idx = (const int*)d_in[1];
    const int*   batch    = (const int*)d_in[2];
    const float* atom_emb = (const float*)d_in[3];
    const float* Ws       = (const float*)d_in[4];
    const float* a_src    = (const float*)d_in[5];
    const float* a_dst    = (const float*)d_in[6];
    const float* biases   = (const float*)d_in[7];
    const float* lin_w    = (const float*)d_in[8];
    const float* lin_b    = (const float*)d_in[9];
    float* out = (float*)d_out;

    char* ws = (char*)d_ws;
    size_t off = 0;
    auto alloc = [&](size_t bytes) -> void* {
        void* p = ws + off;
        off += (bytes + 255) & ~(size_t)255;
        return p;
    };
    unsigned short* bufA  = (unsigned short*)alloc(sizeof(short) * (size_t)N_NODES * D);
    unsigned short* bufB  = (unsigned short*)alloc(sizeof(short) * (size_t)N_NODES * D);
    unsigned short* Wt    = (unsigned short*)alloc(sizeof(short) * NLAYERS * D * D);
    float* s      = (float*)alloc(sizeof(float) * N_NODES);
    float* t      = (float*)alloc(sizeof(float) * N_NODES);
    int*   cnt    = (int*)alloc(sizeof(int) * N_NODES);
    int*   ell    = (int*)alloc(sizeof(int) * (size_t)N_NODES * MAXD);
    int*   growp  = (int*)alloc(sizeof(int) * (NGRAPH + 1));
    float* feats  = (float*)alloc(sizeof(float) * (size_t)NGRAPH * 3 * D);

    const int* esrc = edge_idx;
    const int* edst = edge_idx + N_EDGES;

    seed_kernel<<<SEED_NBLK, 256, 0, stream>>>(cnt, ell);
    init_scatter_fused<<<SCAT_NBLK + ATOM_NBLK + WT_NBLK + GROW_NBLK, 256, 0, stream>>>(
        cnt, ell, Ws, Wt, x, atom_emb, bufA, esrc, edst, batch, growp);

    for (int l = 0; l < NLAYERS; ++l) {
        gemm_bf16<<<(N_NODES + GBM - 1) / GBM, 512, 0, stream>>>(
                                             bufA, Wt + (size_t)l * D * D,
                                             a_src + l * D, a_dst + l * D,
                                             bufB, s, t);
        aggregate_kernel<<<(N_NODES + 3) / 4, 256, 0, stream>>>(bufB, s, t,
                                             cnt, ell, biases + l * D, bufA);
    }

    pool_kernel<<<NGRAPH, 256, 0, stream>>>(bufA, growp, feats);
    final_linear<<<NGRAPH, 512, 0, stream>>>(feats, lin_w, lin_b, out);
}